// Round 1
// baseline (636.193 us; speedup 1.0000x reference)
//
#include <hip/hip_runtime.h>

// ---------------------------------------------------------------------------
// 3-layer GraphSAGE (mean aggregation) + final linear, fp32.
// N=50000 nodes, 128 ch hidden, 800000 edges, out 16 ch.
// Plan: build CSR (dst-indexed) once per call, then per layer:
//   aggregate (gather-mean, 1 wave/node) -> fused GEMM relu(mean@Wl + x@Wr + b)
// ---------------------------------------------------------------------------

__global__ void k_zero_i32(int* __restrict__ p, int n) {
  int i = blockIdx.x * blockDim.x + threadIdx.x;
  if (i < n) p[i] = 0;
}

// Detect whether edge_index arrived as int32 (flag=1) or int64 (flag=0).
// int64 little-endian: odd 32-bit words are high words == 0 (ids < 50000).
// int32: odd words are random node ids; P(1024 consecutive zeros) ~ 0.
__global__ void k_detect(const int* __restrict__ ei, int* __restrict__ flag) {
  int t = threadIdx.x;
  int any = 0;
  for (int i = t; i < 1024; i += 256)
    if (ei[2 * i + 1] != 0) any = 1;
  if (any) atomicOr(flag, 1);
}

__device__ __forceinline__ int load_src(const int* ei, int E, int i, int is32) {
  return is32 ? ei[i] : ei[2 * i];
}
__device__ __forceinline__ int load_dst(const int* ei, int E, int i, int is32) {
  return is32 ? ei[E + i] : ei[2 * E + 2 * i];
}

__global__ __launch_bounds__(256) void k_count(const int* __restrict__ ei,
                                               const int* __restrict__ flag,
                                               int* __restrict__ deg, int E) {
  int i = blockIdx.x * blockDim.x + threadIdx.x;
  if (i < E) {
    int is32 = *flag;
    atomicAdd(&deg[load_dst(ei, E, i, is32)], 1);
  }
}

// Single-block exclusive scan over deg -> row_ptr, cursor (=start), inv_deg.
__global__ __launch_bounds__(1024) void k_scan(const int* __restrict__ deg,
                                               int* __restrict__ row_ptr,
                                               int* __restrict__ cursor,
                                               float* __restrict__ inv_deg, int N) {
  __shared__ int sdata[1024];
  __shared__ int s_base;
  int t = threadIdx.x;
  if (t == 0) s_base = 0;
  __syncthreads();
  for (int start = 0; start < N; start += 1024) {
    int i = start + t;
    int v = (i < N) ? deg[i] : 0;
    sdata[t] = v;
    __syncthreads();
    for (int off = 1; off < 1024; off <<= 1) {
      int add = (t >= off) ? sdata[t - off] : 0;
      __syncthreads();
      sdata[t] += add;
      __syncthreads();
    }
    int excl = sdata[t] - v;
    if (i < N) {
      int rp = s_base + excl;
      row_ptr[i] = rp;
      cursor[i] = rp;
      inv_deg[i] = 1.0f / (float)((v > 1) ? v : 1);
    }
    __syncthreads();
    if (t == 1023) s_base += sdata[1023];
    __syncthreads();
  }
  if (t == 0) row_ptr[N] = s_base;
}

__global__ __launch_bounds__(256) void k_fill(const int* __restrict__ ei,
                                              const int* __restrict__ flag,
                                              int* __restrict__ cursor,
                                              int* __restrict__ col_idx, int E) {
  int i = blockIdx.x * blockDim.x + threadIdx.x;
  if (i < E) {
    int is32 = *flag;
    int d = load_dst(ei, E, i, is32);
    int s = load_src(ei, E, i, is32);
    int p = atomicAdd(&cursor[d], 1);
    col_idx[p] = s;
  }
}

// One wave per node: lanes hold float2 (128 ch). Gather-sum neighbor rows, scale.
__global__ __launch_bounds__(256) void k_aggregate(const float* __restrict__ X,
                                                   const int* __restrict__ row_ptr,
                                                   const int* __restrict__ col_idx,
                                                   const float* __restrict__ inv_deg,
                                                   float* __restrict__ M, int N) {
  int gw = (int)((blockIdx.x * blockDim.x + threadIdx.x) >> 6);
  int lane = threadIdx.x & 63;
  if (gw >= N) return;
  int s = row_ptr[gw], e = row_ptr[gw + 1];
  float ax = 0.f, ay = 0.f;
  for (int j = s; j < e; ++j) {
    int c = col_idx[j];
    float2 v = *reinterpret_cast<const float2*>(&X[(size_t)c * 128 + lane * 2]);
    ax += v.x;
    ay += v.y;
  }
  float inv = inv_deg[gw];
  float2 r;
  r.x = ax * inv;
  r.y = ay * inv;
  *reinterpret_cast<float2*>(&M[(size_t)gw * 128 + lane * 2]) = r;
}

// Fused: Out = relu(Am @ Wl + Ax @ Wr + bias). 64 nodes x 128 cols per block.
__global__ __launch_bounds__(256) void k_sage_gemm(const float* __restrict__ Am,
                                                   const float* __restrict__ Ax,
                                                   const float* __restrict__ Wl,
                                                   const float* __restrict__ Wr,
                                                   const float* __restrict__ bias,
                                                   float* __restrict__ Out, int N) {
  __shared__ float sM[64][32];
  __shared__ float sX[64][32];
  __shared__ float sWl[32][128];
  __shared__ float sWr[32][128];
  int t = threadIdx.x;
  int block_row = blockIdx.x * 64;
  int tc = t & 31, tr = t >> 5;
  int c0 = tc * 4, r0 = tr * 8;
  float acc[8][4];
#pragma unroll
  for (int i = 0; i < 8; ++i)
#pragma unroll
    for (int j = 0; j < 4; ++j) acc[i][j] = 0.f;

  for (int k0 = 0; k0 < 128; k0 += 32) {
    // stage A tiles (64x32 each), float4 per thread x2
#pragma unroll
    for (int l = 0; l < 2; ++l) {
      int j = t + l * 256;
      int row = j >> 3, q = j & 7;
      int g = block_row + row;
      float4 vm, vx;
      if (g < N) {
        vm = *reinterpret_cast<const float4*>(&Am[(size_t)g * 128 + k0 + q * 4]);
        vx = *reinterpret_cast<const float4*>(&Ax[(size_t)g * 128 + k0 + q * 4]);
      } else {
        vm = make_float4(0.f, 0.f, 0.f, 0.f);
        vx = vm;
      }
      *reinterpret_cast<float4*>(&sM[row][q * 4]) = vm;
      *reinterpret_cast<float4*>(&sX[row][q * 4]) = vx;
    }
    // stage W tiles (32x128 each)
#pragma unroll
    for (int l = 0; l < 4; ++l) {
      int j = t + l * 256;
      int row = j >> 5, q = j & 31;
      *reinterpret_cast<float4*>(&sWl[row][q * 4]) =
          *reinterpret_cast<const float4*>(&Wl[(size_t)(k0 + row) * 128 + q * 4]);
      *reinterpret_cast<float4*>(&sWr[row][q * 4]) =
          *reinterpret_cast<const float4*>(&Wr[(size_t)(k0 + row) * 128 + q * 4]);
    }
    __syncthreads();
#pragma unroll 4
    for (int kk = 0; kk < 32; ++kk) {
      float4 wl = *reinterpret_cast<const float4*>(&sWl[kk][c0]);
      float4 wr = *reinterpret_cast<const float4*>(&sWr[kk][c0]);
#pragma unroll
      for (int i = 0; i < 8; ++i) {
        float am = sM[r0 + i][kk];
        float av = sX[r0 + i][kk];
        acc[i][0] = fmaf(am, wl.x, acc[i][0]);
        acc[i][1] = fmaf(am, wl.y, acc[i][1]);
        acc[i][2] = fmaf(am, wl.z, acc[i][2]);
        acc[i][3] = fmaf(am, wl.w, acc[i][3]);
        acc[i][0] = fmaf(av, wr.x, acc[i][0]);
        acc[i][1] = fmaf(av, wr.y, acc[i][1]);
        acc[i][2] = fmaf(av, wr.z, acc[i][2]);
        acc[i][3] = fmaf(av, wr.w, acc[i][3]);
      }
    }
    __syncthreads();
  }
  float4 bv = *reinterpret_cast<const float4*>(&bias[c0]);
#pragma unroll
  for (int i = 0; i < 8; ++i) {
    int g = block_row + r0 + i;
    if (g < N) {
      float4 o;
      o.x = fmaxf(acc[i][0] + bv.x, 0.f);
      o.y = fmaxf(acc[i][1] + bv.y, 0.f);
      o.z = fmaxf(acc[i][2] + bv.z, 0.f);
      o.w = fmaxf(acc[i][3] + bv.w, 0.f);
      *reinterpret_cast<float4*>(&Out[(size_t)g * 128 + c0]) = o;
    }
  }
}

// Final: Out[N][16] = H[N][128] @ W[128][16] + b. 16 nodes/block.
__global__ __launch_bounds__(256) void k_final(const float* __restrict__ H,
                                               const float* __restrict__ W,
                                               const float* __restrict__ b,
                                               float* __restrict__ Out, int N) {
  __shared__ float sH[16][128];
  __shared__ float sW[128][16];
  __shared__ float sb[16];
  int t = threadIdx.x;
  int node0 = blockIdx.x * 16;
  for (int j = t; j < 512; j += 256) {  // 16*128 floats = 512 float4
    int row = j >> 5, q = j & 31;
    int g = node0 + row;
    float4 v = make_float4(0.f, 0.f, 0.f, 0.f);
    if (g < N) v = *reinterpret_cast<const float4*>(&H[(size_t)g * 128 + q * 4]);
    *reinterpret_cast<float4*>(&sH[row][q * 4]) = v;
  }
  for (int j = t; j < 512; j += 256) {  // 128*16 floats = 512 float4
    int row = j >> 2, q = j & 3;
    *reinterpret_cast<float4*>(&sW[row][q * 4]) =
        *reinterpret_cast<const float4*>(&W[(size_t)row * 16 + q * 4]);
  }
  if (t < 16) sb[t] = b[t];
  __syncthreads();
  int node = t >> 4, col = t & 15;
  float acc = sb[col];
#pragma unroll 8
  for (int k = 0; k < 128; ++k) acc = fmaf(sH[node][k], sW[k][col], acc);
  int g = node0 + node;
  if (g < N) Out[(size_t)g * 16 + col] = acc;
}

extern "C" void kernel_launch(void* const* d_in, const int* in_sizes, int n_in,
                              void* d_out, int out_size, void* d_ws, size_t ws_size,
                              hipStream_t stream) {
  if (n_in < 13) return;
  const float* x = (const float*)d_in[0];
  const int* ei = (const int*)d_in[1];
  const float* W1l = (const float*)d_in[2];
  const float* b1 = (const float*)d_in[3];
  const float* W1r = (const float*)d_in[4];
  const float* W2l = (const float*)d_in[5];
  const float* b2 = (const float*)d_in[6];
  const float* W2r = (const float*)d_in[7];
  const float* W3l = (const float*)d_in[8];
  const float* b3 = (const float*)d_in[9];
  const float* W3r = (const float*)d_in[10];
  const float* Wlin = (const float*)d_in[11];
  const float* blin = (const float*)d_in[12];
  float* out = (float*)d_out;

  const int N = in_sizes[0] / 128;
  const int E = in_sizes[1] / 2;

  char* w = (char*)d_ws;
  size_t off = 0;
  auto alloc = [&](size_t bytes) -> void* {
    off = (off + 255) & ~(size_t)255;
    void* p = (void*)(w + off);
    off += bytes;
    return p;
  };
  float* mean = (float*)alloc((size_t)N * 128 * 4);
  float* h1 = (float*)alloc((size_t)N * 128 * 4);
  float* h2 = (float*)alloc((size_t)N * 128 * 4);
  int* deg = (int*)alloc((size_t)N * 4);
  int* row_ptr = (int*)alloc((size_t)(N + 1) * 4);
  int* cursor = (int*)alloc((size_t)N * 4);
  int* col_idx = (int*)alloc((size_t)E * 4);
  float* invdeg = (float*)alloc((size_t)N * 4);
  int* flag = (int*)alloc(4);
  (void)ws_size;

  // CSR build
  k_zero_i32<<<(N + 255) / 256, 256, 0, stream>>>(deg, N);
  k_zero_i32<<<1, 256, 0, stream>>>(flag, 1);
  k_detect<<<1, 256, 0, stream>>>(ei, flag);
  k_count<<<(E + 255) / 256, 256, 0, stream>>>(ei, flag, deg, E);
  k_scan<<<1, 1024, 0, stream>>>(deg, row_ptr, cursor, invdeg, N);
  k_fill<<<(E + 255) / 256, 256, 0, stream>>>(ei, flag, cursor, col_idx, E);

  int aggBlocks = (N * 64 + 255) / 256;
  int gemmBlocks = (N + 63) / 64;

  // layer 1
  k_aggregate<<<aggBlocks, 256, 0, stream>>>(x, row_ptr, col_idx, invdeg, mean, N);
  k_sage_gemm<<<gemmBlocks, 256, 0, stream>>>(mean, x, W1l, W1r, b1, h1, N);
  // layer 2
  k_aggregate<<<aggBlocks, 256, 0, stream>>>(h1, row_ptr, col_idx, invdeg, mean, N);
  k_sage_gemm<<<gemmBlocks, 256, 0, stream>>>(mean, h1, W2l, W2r, b2, h2, N);
  // layer 3
  k_aggregate<<<aggBlocks, 256, 0, stream>>>(h2, row_ptr, col_idx, invdeg, mean, N);
  k_sage_gemm<<<gemmBlocks, 256, 0, stream>>>(mean, h2, W3l, W3r, b3, h1, N);
  // final linear
  k_final<<<(N + 15) / 16, 256, 0, stream>>>(h1, Wlin, blin, out, N);
}

// Round 2
// 551.534 us; speedup vs baseline: 1.1535x; 1.1535x over previous
//
#include <hip/hip_runtime.h>

// ---------------------------------------------------------------------------
// 3-layer GraphSAGE (mean aggregation) + final linear, fp32.
// N=50000 nodes, 128 ch hidden, 800000 edges, out 16 ch.
// CSR built per call: count -> 3-pass device-wide scan -> fill.
// Per layer: aggregate (gather-mean, 1 wave/node) -> fused GEMM
//            relu(mean@Wl + x@Wr + b).
// R1 fix: single-block scan was 97us (1 CU busy); now 3-pass scan ~8us.
// ---------------------------------------------------------------------------

__global__ void k_zero_i32(int* __restrict__ p, int n) {
  int i = blockIdx.x * blockDim.x + threadIdx.x;
  if (i < n) p[i] = 0;
}

// Detect whether edge_index arrived as int32 (flag=1) or int64 (flag=0).
// int64 little-endian: odd 32-bit words are high words == 0 (ids < 50000).
__global__ void k_detect(const int* __restrict__ ei, int* __restrict__ flag) {
  int t = threadIdx.x;
  int any = 0;
  for (int i = t; i < 1024; i += 256)
    if (ei[2 * i + 1] != 0) any = 1;
  if (any) atomicOr(flag, 1);
}

__device__ __forceinline__ int load_src(const int* ei, int E, int i, int is32) {
  return is32 ? ei[i] : ei[2 * i];
}
__device__ __forceinline__ int load_dst(const int* ei, int E, int i, int is32) {
  return is32 ? ei[E + i] : ei[2 * E + 2 * i];
}

__global__ __launch_bounds__(256) void k_count(const int* __restrict__ ei,
                                               const int* __restrict__ flag,
                                               int* __restrict__ deg, int E) {
  int i = blockIdx.x * blockDim.x + threadIdx.x;
  if (i < E) {
    int is32 = *flag;
    atomicAdd(&deg[load_dst(ei, E, i, is32)], 1);
  }
}

// --- device-wide exclusive scan over deg (3 passes, 1024 elems/block) ------
__global__ __launch_bounds__(256) void k_scan1(const int* __restrict__ deg,
                                               int* __restrict__ bsum, int N) {
  __shared__ int s[256];
  int t = threadIdx.x;
  int base = blockIdx.x * 1024 + t * 4;
  int v = 0;
#pragma unroll
  for (int j = 0; j < 4; ++j) {
    int i = base + j;
    v += (i < N) ? deg[i] : 0;
  }
  s[t] = v;
  __syncthreads();
  for (int off = 128; off > 0; off >>= 1) {
    if (t < off) s[t] += s[t + off];
    __syncthreads();
  }
  if (t == 0) bsum[blockIdx.x] = s[0];
}

// single block: exclusive-scan nb block sums in place; total -> row_ptr[N]
__global__ __launch_bounds__(1024) void k_scan2(int* __restrict__ bsum,
                                                int* __restrict__ row_ptr,
                                                int nb, int N) {
  __shared__ int s[1024];
  int t = threadIdx.x;
  int v = (t < nb) ? bsum[t] : 0;
  s[t] = v;
  __syncthreads();
  for (int off = 1; off < 1024; off <<= 1) {
    int add = (t >= off) ? s[t - off] : 0;
    __syncthreads();
    s[t] += add;
    __syncthreads();
  }
  if (t < nb) bsum[t] = s[t] - v;  // exclusive
  if (t == 1023) row_ptr[N] = s[1023];
}

__global__ __launch_bounds__(256) void k_scan3(const int* __restrict__ deg,
                                               const int* __restrict__ bsum,
                                               int* __restrict__ row_ptr,
                                               int* __restrict__ cursor,
                                               float* __restrict__ inv_deg, int N) {
  __shared__ int s[256];
  int t = threadIdx.x;
  int base = blockIdx.x * 1024 + t * 4;
  int v[4];
  int sum = 0;
#pragma unroll
  for (int j = 0; j < 4; ++j) {
    int i = base + j;
    v[j] = (i < N) ? deg[i] : 0;
    sum += v[j];
  }
  s[t] = sum;
  __syncthreads();
  for (int off = 1; off < 256; off <<= 1) {
    int add = (t >= off) ? s[t - off] : 0;
    __syncthreads();
    s[t] += add;
    __syncthreads();
  }
  int excl = s[t] - sum + bsum[blockIdx.x];
#pragma unroll
  for (int j = 0; j < 4; ++j) {
    int i = base + j;
    if (i < N) {
      row_ptr[i] = excl;
      cursor[i] = excl;
      inv_deg[i] = 1.0f / (float)((v[j] > 1) ? v[j] : 1);
      excl += v[j];
    }
  }
}

__global__ __launch_bounds__(256) void k_fill(const int* __restrict__ ei,
                                              const int* __restrict__ flag,
                                              int* __restrict__ cursor,
                                              int* __restrict__ col_idx, int E) {
  int i = blockIdx.x * blockDim.x + threadIdx.x;
  if (i < E) {
    int is32 = *flag;
    int d = load_dst(ei, E, i, is32);
    int s = load_src(ei, E, i, is32);
    int p = atomicAdd(&cursor[d], 1);
    col_idx[p] = s;
  }
}

// One wave per node: lanes hold float2 (128 ch). Gather-sum neighbor rows, scale.
__global__ __launch_bounds__(256) void k_aggregate(const float* __restrict__ X,
                                                   const int* __restrict__ row_ptr,
                                                   const int* __restrict__ col_idx,
                                                   const float* __restrict__ inv_deg,
                                                   float* __restrict__ M, int N) {
  int gw = (int)((blockIdx.x * blockDim.x + threadIdx.x) >> 6);
  int lane = threadIdx.x & 63;
  if (gw >= N) return;
  int s = row_ptr[gw], e = row_ptr[gw + 1];
  float ax = 0.f, ay = 0.f;
  for (int j = s; j < e; ++j) {
    int c = col_idx[j];
    float2 v = *reinterpret_cast<const float2*>(&X[(size_t)c * 128 + lane * 2]);
    ax += v.x;
    ay += v.y;
  }
  float inv = inv_deg[gw];
  float2 r;
  r.x = ax * inv;
  r.y = ay * inv;
  *reinterpret_cast<float2*>(&M[(size_t)gw * 128 + lane * 2]) = r;
}

// Fused: Out = relu(Am @ Wl + Ax @ Wr + bias). 64 nodes x 128 cols per block.
__global__ __launch_bounds__(256) void k_sage_gemm(const float* __restrict__ Am,
                                                   const float* __restrict__ Ax,
                                                   const float* __restrict__ Wl,
                                                   const float* __restrict__ Wr,
                                                   const float* __restrict__ bias,
                                                   float* __restrict__ Out, int N) {
  __shared__ float sM[64][32];
  __shared__ float sX[64][32];
  __shared__ float sWl[32][128];
  __shared__ float sWr[32][128];
  int t = threadIdx.x;
  int block_row = blockIdx.x * 64;
  int tc = t & 31, tr = t >> 5;
  int c0 = tc * 4, r0 = tr * 8;
  float acc[8][4];
#pragma unroll
  for (int i = 0; i < 8; ++i)
#pragma unroll
    for (int j = 0; j < 4; ++j) acc[i][j] = 0.f;

  for (int k0 = 0; k0 < 128; k0 += 32) {
#pragma unroll
    for (int l = 0; l < 2; ++l) {
      int j = t + l * 256;
      int row = j >> 3, q = j & 7;
      int g = block_row + row;
      float4 vm, vx;
      if (g < N) {
        vm = *reinterpret_cast<const float4*>(&Am[(size_t)g * 128 + k0 + q * 4]);
        vx = *reinterpret_cast<const float4*>(&Ax[(size_t)g * 128 + k0 + q * 4]);
      } else {
        vm = make_float4(0.f, 0.f, 0.f, 0.f);
        vx = vm;
      }
      *reinterpret_cast<float4*>(&sM[row][q * 4]) = vm;
      *reinterpret_cast<float4*>(&sX[row][q * 4]) = vx;
    }
#pragma unroll
    for (int l = 0; l < 4; ++l) {
      int j = t + l * 256;
      int row = j >> 5, q = j & 31;
      *reinterpret_cast<float4*>(&sWl[row][q * 4]) =
          *reinterpret_cast<const float4*>(&Wl[(size_t)(k0 + row) * 128 + q * 4]);
      *reinterpret_cast<float4*>(&sWr[row][q * 4]) =
          *reinterpret_cast<const float4*>(&Wr[(size_t)(k0 + row) * 128 + q * 4]);
    }
    __syncthreads();
#pragma unroll 4
    for (int kk = 0; kk < 32; ++kk) {
      float4 wl = *reinterpret_cast<const float4*>(&sWl[kk][c0]);
      float4 wr = *reinterpret_cast<const float4*>(&sWr[kk][c0]);
#pragma unroll
      for (int i = 0; i < 8; ++i) {
        float am = sM[r0 + i][kk];
        float av = sX[r0 + i][kk];
        acc[i][0] = fmaf(am, wl.x, acc[i][0]);
        acc[i][1] = fmaf(am, wl.y, acc[i][1]);
        acc[i][2] = fmaf(am, wl.z, acc[i][2]);
        acc[i][3] = fmaf(am, wl.w, acc[i][3]);
        acc[i][0] = fmaf(av, wr.x, acc[i][0]);
        acc[i][1] = fmaf(av, wr.y, acc[i][1]);
        acc[i][2] = fmaf(av, wr.z, acc[i][2]);
        acc[i][3] = fmaf(av, wr.w, acc[i][3]);
      }
    }
    __syncthreads();
  }
  float4 bv = *reinterpret_cast<const float4*>(&bias[c0]);
#pragma unroll
  for (int i = 0; i < 8; ++i) {
    int g = block_row + r0 + i;
    if (g < N) {
      float4 o;
      o.x = fmaxf(acc[i][0] + bv.x, 0.f);
      o.y = fmaxf(acc[i][1] + bv.y, 0.f);
      o.z = fmaxf(acc[i][2] + bv.z, 0.f);
      o.w = fmaxf(acc[i][3] + bv.w, 0.f);
      *reinterpret_cast<float4*>(&Out[(size_t)g * 128 + c0]) = o;
    }
  }
}

// Final: Out[N][16] = H[N][128] @ W[128][16] + b. 16 nodes/block.
__global__ __launch_bounds__(256) void k_final(const float* __restrict__ H,
                                               const float* __restrict__ W,
                                               const float* __restrict__ b,
                                               float* __restrict__ Out, int N) {
  __shared__ float sH[16][128];
  __shared__ float sW[128][16];
  __shared__ float sb[16];
  int t = threadIdx.x;
  int node0 = blockIdx.x * 16;
  for (int j = t; j < 512; j += 256) {
    int row = j >> 5, q = j & 31;
    int g = node0 + row;
    float4 v = make_float4(0.f, 0.f, 0.f, 0.f);
    if (g < N) v = *reinterpret_cast<const float4*>(&H[(size_t)g * 128 + q * 4]);
    *reinterpret_cast<float4*>(&sH[row][q * 4]) = v;
  }
  for (int j = t; j < 512; j += 256) {
    int row = j >> 2, q = j & 3;
    *reinterpret_cast<float4*>(&sW[row][q * 4]) =
        *reinterpret_cast<const float4*>(&W[(size_t)row * 16 + q * 4]);
  }
  if (t < 16) sb[t] = b[t];
  __syncthreads();
  int node = t >> 4, col = t & 15;
  float acc = sb[col];
#pragma unroll 8
  for (int k = 0; k < 128; ++k) acc = fmaf(sH[node][k], sW[k][col], acc);
  int g = node0 + node;
  if (g < N) Out[(size_t)g * 16 + col] = acc;
}

extern "C" void kernel_launch(void* const* d_in, const int* in_sizes, int n_in,
                              void* d_out, int out_size, void* d_ws, size_t ws_size,
                              hipStream_t stream) {
  if (n_in < 13) return;
  const float* x = (const float*)d_in[0];
  const int* ei = (const int*)d_in[1];
  const float* W1l = (const float*)d_in[2];
  const float* b1 = (const float*)d_in[3];
  const float* W1r = (const float*)d_in[4];
  const float* W2l = (const float*)d_in[5];
  const float* b2 = (const float*)d_in[6];
  const float* W2r = (const float*)d_in[7];
  const float* W3l = (const float*)d_in[8];
  const float* b3 = (const float*)d_in[9];
  const float* W3r = (const float*)d_in[10];
  const float* Wlin = (const float*)d_in[11];
  const float* blin = (const float*)d_in[12];
  float* out = (float*)d_out;

  const int N = in_sizes[0] / 128;
  const int E = in_sizes[1] / 2;

  char* w = (char*)d_ws;
  size_t off = 0;
  auto alloc = [&](size_t bytes) -> void* {
    off = (off + 255) & ~(size_t)255;
    void* p = (void*)(w + off);
    off += bytes;
    return p;
  };
  float* mean = (float*)alloc((size_t)N * 128 * 4);
  float* h1 = (float*)alloc((size_t)N * 128 * 4);
  float* h2 = (float*)alloc((size_t)N * 128 * 4);
  int* deg = (int*)alloc((size_t)N * 4);
  int* row_ptr = (int*)alloc((size_t)(N + 1) * 4);
  int* cursor = (int*)alloc((size_t)N * 4);
  int* col_idx = (int*)alloc((size_t)E * 4);
  float* invdeg = (float*)alloc((size_t)N * 4);
  int* flag = (int*)alloc(4);
  int* bsum = (int*)alloc((size_t)1024 * 4);
  (void)ws_size;

  const int nbScan = (N + 1023) / 1024;

  // CSR build
  k_zero_i32<<<(N + 255) / 256, 256, 0, stream>>>(deg, N);
  k_zero_i32<<<1, 256, 0, stream>>>(flag, 1);
  k_detect<<<1, 256, 0, stream>>>(ei, flag);
  k_count<<<(E + 255) / 256, 256, 0, stream>>>(ei, flag, deg, E);
  k_scan1<<<nbScan, 256, 0, stream>>>(deg, bsum, N);
  k_scan2<<<1, 1024, 0, stream>>>(bsum, row_ptr, nbScan, N);
  k_scan3<<<nbScan, 256, 0, stream>>>(deg, bsum, row_ptr, cursor, invdeg, N);
  k_fill<<<(E + 255) / 256, 256, 0, stream>>>(ei, flag, cursor, col_idx, E);

  int aggBlocks = (N * 64 + 255) / 256;
  int gemmBlocks = (N + 63) / 64;

  // layer 1
  k_aggregate<<<aggBlocks, 256, 0, stream>>>(x, row_ptr, col_idx, invdeg, mean, N);
  k_sage_gemm<<<gemmBlocks, 256, 0, stream>>>(mean, x, W1l, W1r, b1, h1, N);
  // layer 2
  k_aggregate<<<aggBlocks, 256, 0, stream>>>(h1, row_ptr, col_idx, invdeg, mean, N);
  k_sage_gemm<<<gemmBlocks, 256, 0, stream>>>(mean, h1, W2l, W2r, b2, h2, N);
  // layer 3
  k_aggregate<<<aggBlocks, 256, 0, stream>>>(h2, row_ptr, col_idx, invdeg, mean, N);
  k_sage_gemm<<<gemmBlocks, 256, 0, stream>>>(mean, h2, W3l, W3r, b3, h1, N);
  // final linear
  k_final<<<(N + 15) / 16, 256, 0, stream>>>(h1, Wlin, blin, out, N);
}

// Round 3
// 426.683 us; speedup vs baseline: 1.4910x; 1.2926x over previous
//
#include <hip/hip_runtime.h>

// ---------------------------------------------------------------------------
// 3-layer GraphSAGE (mean aggregation) + final linear.
// N=50000 nodes, 128 ch hidden, 800000 edges, out 16 ch.
// CSR per call (count -> 3-pass scan -> fill). Per layer:
//   aggregate (gather-mean over bf16 copy, fp32 accum) ->
//   fused GEMM relu(mean@Wl + x@Wr + b) in fp32 (+ bf16 copy for next gather).
// R2 fix: gather was latency-bound (1 VMEM in flight) + L2-thrashing;
//         now bf16 rows (halved bytes/working set) + unroll-4 MLP.
// ---------------------------------------------------------------------------

__device__ __forceinline__ float bf16_to_f32(unsigned int lo16) {
  unsigned int u = lo16 << 16;
  return __builtin_bit_cast(float, u);
}
__device__ __forceinline__ unsigned short f32_to_bf16(float f) {
  unsigned int u = __builtin_bit_cast(unsigned int, f);
  unsigned int r = (u + 0x7FFFu + ((u >> 16) & 1u)) >> 16;  // RNE
  return (unsigned short)r;
}

__global__ void k_zero_i32(int* __restrict__ p, int n) {
  int i = blockIdx.x * blockDim.x + threadIdx.x;
  if (i < n) p[i] = 0;
}

// fp32 -> bf16 cast (4 elems/thread)
__global__ __launch_bounds__(256) void k_cast_bf16(const float* __restrict__ in,
                                                   unsigned short* __restrict__ outb,
                                                   int n4) {
  int i = blockIdx.x * blockDim.x + threadIdx.x;
  if (i < n4) {
    float4 v = *reinterpret_cast<const float4*>(&in[(size_t)i * 4]);
    ushort4 o;
    o.x = f32_to_bf16(v.x);
    o.y = f32_to_bf16(v.y);
    o.z = f32_to_bf16(v.z);
    o.w = f32_to_bf16(v.w);
    *reinterpret_cast<ushort4*>(&outb[(size_t)i * 4]) = o;
  }
}

// Detect whether edge_index arrived as int32 (flag=1) or int64 (flag=0).
__global__ void k_detect(const int* __restrict__ ei, int* __restrict__ flag) {
  int t = threadIdx.x;
  int any = 0;
  for (int i = t; i < 1024; i += 256)
    if (ei[2 * i + 1] != 0) any = 1;
  if (any) atomicOr(flag, 1);
}

__device__ __forceinline__ int load_src(const int* ei, int E, int i, int is32) {
  return is32 ? ei[i] : ei[2 * i];
}
__device__ __forceinline__ int load_dst(const int* ei, int E, int i, int is32) {
  return is32 ? ei[E + i] : ei[2 * E + 2 * i];
}

__global__ __launch_bounds__(256) void k_count(const int* __restrict__ ei,
                                               const int* __restrict__ flag,
                                               int* __restrict__ deg, int E) {
  int i = blockIdx.x * blockDim.x + threadIdx.x;
  if (i < E) {
    int is32 = *flag;
    atomicAdd(&deg[load_dst(ei, E, i, is32)], 1);
  }
}

// --- device-wide exclusive scan over deg (3 passes, 1024 elems/block) ------
__global__ __launch_bounds__(256) void k_scan1(const int* __restrict__ deg,
                                               int* __restrict__ bsum, int N) {
  __shared__ int s[256];
  int t = threadIdx.x;
  int base = blockIdx.x * 1024 + t * 4;
  int v = 0;
#pragma unroll
  for (int j = 0; j < 4; ++j) {
    int i = base + j;
    v += (i < N) ? deg[i] : 0;
  }
  s[t] = v;
  __syncthreads();
  for (int off = 128; off > 0; off >>= 1) {
    if (t < off) s[t] += s[t + off];
    __syncthreads();
  }
  if (t == 0) bsum[blockIdx.x] = s[0];
}

__global__ __launch_bounds__(1024) void k_scan2(int* __restrict__ bsum,
                                                int* __restrict__ row_ptr,
                                                int nb, int N) {
  __shared__ int s[1024];
  int t = threadIdx.x;
  int v = (t < nb) ? bsum[t] : 0;
  s[t] = v;
  __syncthreads();
  for (int off = 1; off < 1024; off <<= 1) {
    int add = (t >= off) ? s[t - off] : 0;
    __syncthreads();
    s[t] += add;
    __syncthreads();
  }
  if (t < nb) bsum[t] = s[t] - v;  // exclusive
  if (t == 1023) row_ptr[N] = s[1023];
}

__global__ __launch_bounds__(256) void k_scan3(const int* __restrict__ deg,
                                               const int* __restrict__ bsum,
                                               int* __restrict__ row_ptr,
                                               int* __restrict__ cursor,
                                               float* __restrict__ inv_deg, int N) {
  __shared__ int s[256];
  int t = threadIdx.x;
  int base = blockIdx.x * 1024 + t * 4;
  int v[4];
  int sum = 0;
#pragma unroll
  for (int j = 0; j < 4; ++j) {
    int i = base + j;
    v[j] = (i < N) ? deg[i] : 0;
    sum += v[j];
  }
  s[t] = sum;
  __syncthreads();
  for (int off = 1; off < 256; off <<= 1) {
    int add = (t >= off) ? s[t - off] : 0;
    __syncthreads();
    s[t] += add;
    __syncthreads();
  }
  int excl = s[t] - sum + bsum[blockIdx.x];
#pragma unroll
  for (int j = 0; j < 4; ++j) {
    int i = base + j;
    if (i < N) {
      row_ptr[i] = excl;
      cursor[i] = excl;
      inv_deg[i] = 1.0f / (float)((v[j] > 1) ? v[j] : 1);
      excl += v[j];
    }
  }
}

__global__ __launch_bounds__(256) void k_fill(const int* __restrict__ ei,
                                              const int* __restrict__ flag,
                                              int* __restrict__ cursor,
                                              int* __restrict__ col_idx, int E) {
  int i = blockIdx.x * blockDim.x + threadIdx.x;
  if (i < E) {
    int is32 = *flag;
    int d = load_dst(ei, E, i, is32);
    int s = load_src(ei, E, i, is32);
    int p = atomicAdd(&cursor[d], 1);
    col_idx[p] = s;
  }
}

// One wave per node. Gather bf16 rows (2 ch/lane packed in u32), fp32 accum.
// Unroll-4: 4 independent row-gathers in flight per wave.
__global__ __launch_bounds__(256) void k_aggregate(const unsigned short* __restrict__ Xb,
                                                   const int* __restrict__ row_ptr,
                                                   const int* __restrict__ col_idx,
                                                   const float* __restrict__ inv_deg,
                                                   float* __restrict__ M, int N) {
  int gw = (int)((blockIdx.x * blockDim.x + threadIdx.x) >> 6);
  int lane = threadIdx.x & 63;
  if (gw >= N) return;
  int s = row_ptr[gw], e = row_ptr[gw + 1];
  float ax0 = 0.f, ay0 = 0.f, ax1 = 0.f, ay1 = 0.f;
  float ax2 = 0.f, ay2 = 0.f, ax3 = 0.f, ay3 = 0.f;
  int j = s;
  for (; j + 4 <= e; j += 4) {
    int c0 = col_idx[j], c1 = col_idx[j + 1], c2 = col_idx[j + 2], c3 = col_idx[j + 3];
    unsigned int v0 = *reinterpret_cast<const unsigned int*>(&Xb[(size_t)c0 * 128 + lane * 2]);
    unsigned int v1 = *reinterpret_cast<const unsigned int*>(&Xb[(size_t)c1 * 128 + lane * 2]);
    unsigned int v2 = *reinterpret_cast<const unsigned int*>(&Xb[(size_t)c2 * 128 + lane * 2]);
    unsigned int v3 = *reinterpret_cast<const unsigned int*>(&Xb[(size_t)c3 * 128 + lane * 2]);
    ax0 += bf16_to_f32(v0 & 0xFFFFu);
    ay0 += bf16_to_f32(v0 >> 16);
    ax1 += bf16_to_f32(v1 & 0xFFFFu);
    ay1 += bf16_to_f32(v1 >> 16);
    ax2 += bf16_to_f32(v2 & 0xFFFFu);
    ay2 += bf16_to_f32(v2 >> 16);
    ax3 += bf16_to_f32(v3 & 0xFFFFu);
    ay3 += bf16_to_f32(v3 >> 16);
  }
  for (; j < e; ++j) {
    int c = col_idx[j];
    unsigned int v = *reinterpret_cast<const unsigned int*>(&Xb[(size_t)c * 128 + lane * 2]);
    ax0 += bf16_to_f32(v & 0xFFFFu);
    ay0 += bf16_to_f32(v >> 16);
  }
  float inv = inv_deg[gw];
  float2 r;
  r.x = (ax0 + ax1 + ax2 + ax3) * inv;
  r.y = (ay0 + ay1 + ay2 + ay3) * inv;
  *reinterpret_cast<float2*>(&M[(size_t)gw * 128 + lane * 2]) = r;
}

// Fused: Out = relu(Am @ Wl + Ax @ Wr + bias); optional bf16 copy of Out.
__global__ __launch_bounds__(256) void k_sage_gemm(const float* __restrict__ Am,
                                                   const float* __restrict__ Ax,
                                                   const float* __restrict__ Wl,
                                                   const float* __restrict__ Wr,
                                                   const float* __restrict__ bias,
                                                   float* __restrict__ Out,
                                                   unsigned short* __restrict__ OutB,
                                                   int N) {
  __shared__ float sM[64][32];
  __shared__ float sX[64][32];
  __shared__ float sWl[32][128];
  __shared__ float sWr[32][128];
  int t = threadIdx.x;
  int block_row = blockIdx.x * 64;
  int tc = t & 31, tr = t >> 5;
  int c0 = tc * 4, r0 = tr * 8;
  float acc[8][4];
#pragma unroll
  for (int i = 0; i < 8; ++i)
#pragma unroll
    for (int j = 0; j < 4; ++j) acc[i][j] = 0.f;

  for (int k0 = 0; k0 < 128; k0 += 32) {
#pragma unroll
    for (int l = 0; l < 2; ++l) {
      int j = t + l * 256;
      int row = j >> 3, q = j & 7;
      int g = block_row + row;
      float4 vm, vx;
      if (g < N) {
        vm = *reinterpret_cast<const float4*>(&Am[(size_t)g * 128 + k0 + q * 4]);
        vx = *reinterpret_cast<const float4*>(&Ax[(size_t)g * 128 + k0 + q * 4]);
      } else {
        vm = make_float4(0.f, 0.f, 0.f, 0.f);
        vx = vm;
      }
      *reinterpret_cast<float4*>(&sM[row][q * 4]) = vm;
      *reinterpret_cast<float4*>(&sX[row][q * 4]) = vx;
    }
#pragma unroll
    for (int l = 0; l < 4; ++l) {
      int j = t + l * 256;
      int row = j >> 5, q = j & 31;
      *reinterpret_cast<float4*>(&sWl[row][q * 4]) =
          *reinterpret_cast<const float4*>(&Wl[(size_t)(k0 + row) * 128 + q * 4]);
      *reinterpret_cast<float4*>(&sWr[row][q * 4]) =
          *reinterpret_cast<const float4*>(&Wr[(size_t)(k0 + row) * 128 + q * 4]);
    }
    __syncthreads();
#pragma unroll 4
    for (int kk = 0; kk < 32; ++kk) {
      float4 wl = *reinterpret_cast<const float4*>(&sWl[kk][c0]);
      float4 wr = *reinterpret_cast<const float4*>(&sWr[kk][c0]);
#pragma unroll
      for (int i = 0; i < 8; ++i) {
        float am = sM[r0 + i][kk];
        float av = sX[r0 + i][kk];
        acc[i][0] = fmaf(am, wl.x, acc[i][0]);
        acc[i][1] = fmaf(am, wl.y, acc[i][1]);
        acc[i][2] = fmaf(am, wl.z, acc[i][2]);
        acc[i][3] = fmaf(am, wl.w, acc[i][3]);
        acc[i][0] = fmaf(av, wr.x, acc[i][0]);
        acc[i][1] = fmaf(av, wr.y, acc[i][1]);
        acc[i][2] = fmaf(av, wr.z, acc[i][2]);
        acc[i][3] = fmaf(av, wr.w, acc[i][3]);
      }
    }
    __syncthreads();
  }
  float4 bv = *reinterpret_cast<const float4*>(&bias[c0]);
#pragma unroll
  for (int i = 0; i < 8; ++i) {
    int g = block_row + r0 + i;
    if (g < N) {
      float4 o;
      o.x = fmaxf(acc[i][0] + bv.x, 0.f);
      o.y = fmaxf(acc[i][1] + bv.y, 0.f);
      o.z = fmaxf(acc[i][2] + bv.z, 0.f);
      o.w = fmaxf(acc[i][3] + bv.w, 0.f);
      *reinterpret_cast<float4*>(&Out[(size_t)g * 128 + c0]) = o;
      if (OutB) {
        ushort4 ob;
        ob.x = f32_to_bf16(o.x);
        ob.y = f32_to_bf16(o.y);
        ob.z = f32_to_bf16(o.z);
        ob.w = f32_to_bf16(o.w);
        *reinterpret_cast<ushort4*>(&OutB[(size_t)g * 128 + c0]) = ob;
      }
    }
  }
}

// Final: Out[N][16] = H[N][128] @ W[128][16] + b. 16 nodes/block.
__global__ __launch_bounds__(256) void k_final(const float* __restrict__ H,
                                               const float* __restrict__ W,
                                               const float* __restrict__ b,
                                               float* __restrict__ Out, int N) {
  __shared__ float sH[16][128];
  __shared__ float sW[128][16];
  __shared__ float sb[16];
  int t = threadIdx.x;
  int node0 = blockIdx.x * 16;
  for (int j = t; j < 512; j += 256) {
    int row = j >> 5, q = j & 31;
    int g = node0 + row;
    float4 v = make_float4(0.f, 0.f, 0.f, 0.f);
    if (g < N) v = *reinterpret_cast<const float4*>(&H[(size_t)g * 128 + q * 4]);
    *reinterpret_cast<float4*>(&sH[row][q * 4]) = v;
  }
  for (int j = t; j < 512; j += 256) {
    int row = j >> 2, q = j & 3;
    *reinterpret_cast<float4*>(&sW[row][q * 4]) =
        *reinterpret_cast<const float4*>(&W[(size_t)row * 16 + q * 4]);
  }
  if (t < 16) sb[t] = b[t];
  __syncthreads();
  int node = t >> 4, col = t & 15;
  float acc = sb[col];
#pragma unroll 8
  for (int k = 0; k < 128; ++k) acc = fmaf(sH[node][k], sW[k][col], acc);
  int g = node0 + node;
  if (g < N) Out[(size_t)g * 16 + col] = acc;
}

extern "C" void kernel_launch(void* const* d_in, const int* in_sizes, int n_in,
                              void* d_out, int out_size, void* d_ws, size_t ws_size,
                              hipStream_t stream) {
  if (n_in < 13) return;
  const float* x = (const float*)d_in[0];
  const int* ei = (const int*)d_in[1];
  const float* W1l = (const float*)d_in[2];
  const float* b1 = (const float*)d_in[3];
  const float* W1r = (const float*)d_in[4];
  const float* W2l = (const float*)d_in[5];
  const float* b2 = (const float*)d_in[6];
  const float* W2r = (const float*)d_in[7];
  const float* W3l = (const float*)d_in[8];
  const float* b3 = (const float*)d_in[9];
  const float* W3r = (const float*)d_in[10];
  const float* Wlin = (const float*)d_in[11];
  const float* blin = (const float*)d_in[12];
  float* out = (float*)d_out;

  const int N = in_sizes[0] / 128;
  const int E = in_sizes[1] / 2;

  char* w = (char*)d_ws;
  size_t off = 0;
  auto alloc = [&](size_t bytes) -> void* {
    off = (off + 255) & ~(size_t)255;
    void* p = (void*)(w + off);
    off += bytes;
    return p;
  };
  float* mean = (float*)alloc((size_t)N * 128 * 4);
  float* h1 = (float*)alloc((size_t)N * 128 * 4);
  float* h2 = (float*)alloc((size_t)N * 128 * 4);
  unsigned short* gb = (unsigned short*)alloc((size_t)N * 128 * 2);  // bf16 gather src
  int* deg = (int*)alloc((size_t)N * 4);
  int* row_ptr = (int*)alloc((size_t)(N + 1) * 4);
  int* cursor = (int*)alloc((size_t)N * 4);
  int* col_idx = (int*)alloc((size_t)E * 4);
  float* invdeg = (float*)alloc((size_t)N * 4);
  int* flag = (int*)alloc(4);
  int* bsum = (int*)alloc((size_t)1024 * 4);
  (void)ws_size;

  const int nbScan = (N + 1023) / 1024;

  // CSR build (+ bf16 cast of x overlapped in the same stream order)
  k_zero_i32<<<(N + 255) / 256, 256, 0, stream>>>(deg, N);
  k_zero_i32<<<1, 256, 0, stream>>>(flag, 1);
  k_detect<<<1, 256, 0, stream>>>(ei, flag);
  k_count<<<(E + 255) / 256, 256, 0, stream>>>(ei, flag, deg, E);
  k_cast_bf16<<<(N * 32 + 255) / 256, 256, 0, stream>>>(x, gb, N * 32);
  k_scan1<<<nbScan, 256, 0, stream>>>(deg, bsum, N);
  k_scan2<<<1, 1024, 0, stream>>>(bsum, row_ptr, nbScan, N);
  k_scan3<<<nbScan, 256, 0, stream>>>(deg, bsum, row_ptr, cursor, invdeg, N);
  k_fill<<<(E + 255) / 256, 256, 0, stream>>>(ei, flag, cursor, col_idx, E);

  int aggBlocks = (N * 64 + 255) / 256;
  int gemmBlocks = (N + 63) / 64;

  // layer 1
  k_aggregate<<<aggBlocks, 256, 0, stream>>>(gb, row_ptr, col_idx, invdeg, mean, N);
  k_sage_gemm<<<gemmBlocks, 256, 0, stream>>>(mean, x, W1l, W1r, b1, h1, gb, N);
  // layer 2
  k_aggregate<<<aggBlocks, 256, 0, stream>>>(gb, row_ptr, col_idx, invdeg, mean, N);
  k_sage_gemm<<<gemmBlocks, 256, 0, stream>>>(mean, h1, W2l, W2r, b2, h2, gb, N);
  // layer 3
  k_aggregate<<<aggBlocks, 256, 0, stream>>>(gb, row_ptr, col_idx, invdeg, mean, N);
  k_sage_gemm<<<gemmBlocks, 256, 0, stream>>>(mean, h2, W3l, W3r, b3, h1, (unsigned short*)nullptr, N);
  // final linear
  k_final<<<(N + 15) / 16, 256, 0, stream>>>(h1, Wlin, blin, out, N);
}

// Round 4
// 290.773 us; speedup vs baseline: 2.1879x; 1.4674x over previous
//
#include <hip/hip_runtime.h>

// ---------------------------------------------------------------------------
// 3-layer GraphSAGE (mean aggregation) + final linear.
// N=50000, 128 ch hidden, 800000 edges, out 16.
// R4: GEMMs moved to bf16 MFMA with hi/lo split (3-pass: fp32-quality).
//     Combined K=256 GEMM: [mean | act] @ [Wl ; Wr] (transposed, split, staged
//     via global_load_lds). All activations stored as bf16 hi/lo pairs.
//     k_fill de-atomic'd via edge ranks captured in k_count.
// ---------------------------------------------------------------------------

typedef short bf16x8 __attribute__((ext_vector_type(8)));  // 8 bf16 (4 VGPRs)
typedef float f32x4 __attribute__((ext_vector_type(4)));

__device__ __forceinline__ float bf16_to_f32(unsigned int lo16) {
  unsigned int u = lo16 << 16;
  return __builtin_bit_cast(float, u);
}
__device__ __forceinline__ unsigned short f32_to_bf16(float f) {
  unsigned int u = __builtin_bit_cast(unsigned int, f);
  unsigned int r = (u + 0x7FFFu + ((u >> 16) & 1u)) >> 16;  // RNE
  return (unsigned short)r;
}

// async global->LDS, 16B per lane; lds base must be wave-uniform.
__device__ __forceinline__ void gload_lds16(void* g, void* lds_base) {
  __builtin_amdgcn_global_load_lds(
      (__attribute__((address_space(1))) unsigned int*)(uintptr_t)g,
      (__attribute__((address_space(3))) unsigned int*)(unsigned int)(uintptr_t)lds_base,
      16, 0, 0);
}

__global__ void k_zero_i32(int* __restrict__ p, int n) {
  int i = blockIdx.x * blockDim.x + threadIdx.x;
  if (i < n) p[i] = 0;
}

// fp32 -> bf16 hi/lo split, 4 elems/thread
__global__ __launch_bounds__(256) void k_split(const float* __restrict__ in,
                                               unsigned short* __restrict__ hi,
                                               unsigned short* __restrict__ lo, int n4) {
  int i = blockIdx.x * blockDim.x + threadIdx.x;
  if (i < n4) {
    float4 v = *reinterpret_cast<const float4*>(&in[(size_t)i * 4]);
    ushort4 h, l;
    h.x = f32_to_bf16(v.x); l.x = f32_to_bf16(v.x - bf16_to_f32(h.x));
    h.y = f32_to_bf16(v.y); l.y = f32_to_bf16(v.y - bf16_to_f32(h.y));
    h.z = f32_to_bf16(v.z); l.z = f32_to_bf16(v.z - bf16_to_f32(h.z));
    h.w = f32_to_bf16(v.w); l.w = f32_to_bf16(v.w - bf16_to_f32(h.w));
    *reinterpret_cast<ushort4*>(&hi[(size_t)i * 4]) = h;
    *reinterpret_cast<ushort4*>(&lo[(size_t)i * 4]) = l;
  }
}

// Weights: Wt[n][k] = (k<128 ? Wl[k][n] : Wr[k-128][n]), split hi/lo.
__global__ __launch_bounds__(256) void k_prep_w(const float* __restrict__ Wl,
                                                const float* __restrict__ Wr,
                                                unsigned short* __restrict__ Whi,
                                                unsigned short* __restrict__ Wlo) {
  int n = blockIdx.x, k = threadIdx.x;  // 128 blocks x 256 threads
  float v = (k < 128) ? Wl[(size_t)k * 128 + n] : Wr[(size_t)(k - 128) * 128 + n];
  unsigned short h = f32_to_bf16(v);
  Whi[(size_t)n * 256 + k] = h;
  Wlo[(size_t)n * 256 + k] = f32_to_bf16(v - bf16_to_f32(h));
}

// int32-vs-int64 edge_index detection
__global__ void k_detect(const int* __restrict__ ei, int* __restrict__ flag) {
  int t = threadIdx.x;
  int any = 0;
  for (int i = t; i < 1024; i += 256)
    if (ei[2 * i + 1] != 0) any = 1;
  if (any) atomicOr(flag, 1);
}

__device__ __forceinline__ int load_src(const int* ei, int E, int i, int is32) {
  return is32 ? ei[i] : ei[2 * i];
}
__device__ __forceinline__ int load_dst(const int* ei, int E, int i, int is32) {
  return is32 ? ei[E + i] : ei[2 * E + 2 * i];
}

// count degree + capture per-edge rank (removes atomic from k_fill)
__global__ __launch_bounds__(256) void k_count(const int* __restrict__ ei,
                                               const int* __restrict__ flag,
                                               int* __restrict__ deg,
                                               int* __restrict__ erank, int E) {
  int i = blockIdx.x * blockDim.x + threadIdx.x;
  if (i < E) {
    int is32 = *flag;
    erank[i] = atomicAdd(&deg[load_dst(ei, E, i, is32)], 1);
  }
}

// --- device-wide exclusive scan over deg (3 passes, 1024 elems/block) ------
__global__ __launch_bounds__(256) void k_scan1(const int* __restrict__ deg,
                                               int* __restrict__ bsum, int N) {
  __shared__ int s[256];
  int t = threadIdx.x;
  int base = blockIdx.x * 1024 + t * 4;
  int v = 0;
#pragma unroll
  for (int j = 0; j < 4; ++j) {
    int i = base + j;
    v += (i < N) ? deg[i] : 0;
  }
  s[t] = v;
  __syncthreads();
  for (int off = 128; off > 0; off >>= 1) {
    if (t < off) s[t] += s[t + off];
    __syncthreads();
  }
  if (t == 0) bsum[blockIdx.x] = s[0];
}

__global__ __launch_bounds__(1024) void k_scan2(int* __restrict__ bsum,
                                                int* __restrict__ row_ptr,
                                                int nb, int N) {
  __shared__ int s[1024];
  int t = threadIdx.x;
  int v = (t < nb) ? bsum[t] : 0;
  s[t] = v;
  __syncthreads();
  for (int off = 1; off < 1024; off <<= 1) {
    int add = (t >= off) ? s[t - off] : 0;
    __syncthreads();
    s[t] += add;
    __syncthreads();
  }
  if (t < nb) bsum[t] = s[t] - v;  // exclusive
  if (t == 1023) row_ptr[N] = s[1023];
}

__global__ __launch_bounds__(256) void k_scan3(const int* __restrict__ deg,
                                               const int* __restrict__ bsum,
                                               int* __restrict__ row_ptr,
                                               float* __restrict__ inv_deg, int N) {
  __shared__ int s[256];
  int t = threadIdx.x;
  int base = blockIdx.x * 1024 + t * 4;
  int v[4];
  int sum = 0;
#pragma unroll
  for (int j = 0; j < 4; ++j) {
    int i = base + j;
    v[j] = (i < N) ? deg[i] : 0;
    sum += v[j];
  }
  s[t] = sum;
  __syncthreads();
  for (int off = 1; off < 256; off <<= 1) {
    int add = (t >= off) ? s[t - off] : 0;
    __syncthreads();
    s[t] += add;
    __syncthreads();
  }
  int excl = s[t] - sum + bsum[blockIdx.x];
#pragma unroll
  for (int j = 0; j < 4; ++j) {
    int i = base + j;
    if (i < N) {
      row_ptr[i] = excl;
      inv_deg[i] = 1.0f / (float)((v[j] > 1) ? v[j] : 1);
      excl += v[j];
    }
  }
}

// pure scatter fill (rank precomputed)
__global__ __launch_bounds__(256) void k_fill(const int* __restrict__ ei,
                                              const int* __restrict__ flag,
                                              const int* __restrict__ row_ptr,
                                              const int* __restrict__ erank,
                                              int* __restrict__ col_idx, int E) {
  int i = blockIdx.x * blockDim.x + threadIdx.x;
  if (i < E) {
    int is32 = *flag;
    int d = load_dst(ei, E, i, is32);
    int s = load_src(ei, E, i, is32);
    col_idx[row_ptr[d] + erank[i]] = s;
  }
}

// One wave/node: gather bf16(hi) rows, fp32 accum, emit mean as bf16 hi/lo.
__global__ __launch_bounds__(256) void k_aggregate(const unsigned short* __restrict__ Xhi,
                                                   const int* __restrict__ row_ptr,
                                                   const int* __restrict__ col_idx,
                                                   const float* __restrict__ inv_deg,
                                                   unsigned int* __restrict__ Mhi,
                                                   unsigned int* __restrict__ Mlo, int N) {
  int gw = (int)((blockIdx.x * blockDim.x + threadIdx.x) >> 6);
  int lane = threadIdx.x & 63;
  if (gw >= N) return;
  int s = row_ptr[gw], e = row_ptr[gw + 1];
  float ax0 = 0.f, ay0 = 0.f, ax1 = 0.f, ay1 = 0.f;
  float ax2 = 0.f, ay2 = 0.f, ax3 = 0.f, ay3 = 0.f;
  int j = s;
  for (; j + 4 <= e; j += 4) {
    int c0 = col_idx[j], c1 = col_idx[j + 1], c2 = col_idx[j + 2], c3 = col_idx[j + 3];
    unsigned int v0 = *reinterpret_cast<const unsigned int*>(&Xhi[(size_t)c0 * 128 + lane * 2]);
    unsigned int v1 = *reinterpret_cast<const unsigned int*>(&Xhi[(size_t)c1 * 128 + lane * 2]);
    unsigned int v2 = *reinterpret_cast<const unsigned int*>(&Xhi[(size_t)c2 * 128 + lane * 2]);
    unsigned int v3 = *reinterpret_cast<const unsigned int*>(&Xhi[(size_t)c3 * 128 + lane * 2]);
    ax0 += bf16_to_f32(v0 & 0xFFFFu); ay0 += bf16_to_f32(v0 >> 16);
    ax1 += bf16_to_f32(v1 & 0xFFFFu); ay1 += bf16_to_f32(v1 >> 16);
    ax2 += bf16_to_f32(v2 & 0xFFFFu); ay2 += bf16_to_f32(v2 >> 16);
    ax3 += bf16_to_f32(v3 & 0xFFFFu); ay3 += bf16_to_f32(v3 >> 16);
  }
  for (; j < e; ++j) {
    int c = col_idx[j];
    unsigned int v = *reinterpret_cast<const unsigned int*>(&Xhi[(size_t)c * 128 + lane * 2]);
    ax0 += bf16_to_f32(v & 0xFFFFu); ay0 += bf16_to_f32(v >> 16);
  }
  float inv = inv_deg[gw];
  float rx = (ax0 + ax1 + ax2 + ax3) * inv;
  float ry = (ay0 + ay1 + ay2 + ay3) * inv;
  unsigned int hx = f32_to_bf16(rx), hy = f32_to_bf16(ry);
  unsigned int lx = f32_to_bf16(rx - bf16_to_f32(hx));
  unsigned int ly = f32_to_bf16(ry - bf16_to_f32(hy));
  Mhi[(size_t)gw * 64 + lane] = hx | (hy << 16);
  Mlo[(size_t)gw * 64 + lane] = lx | (ly << 16);
}

// MFMA GEMM: Out = relu([A1 | A2](N x 256) @ Wt^T + bias), split-bf16 3-pass.
// A1/A2/W given as bf16 hi/lo. Out emitted as bf16 hi/lo.
// Block: 128 rows x 128 cols, 4 waves (2x2), wave = 64x64 via 4x4 16x16x32 MFMA.
__global__ __launch_bounds__(256) void k_mfma_gemm(
    const unsigned short* __restrict__ A1hi, const unsigned short* __restrict__ A1lo,
    const unsigned short* __restrict__ A2hi, const unsigned short* __restrict__ A2lo,
    const unsigned short* __restrict__ Whi, const unsigned short* __restrict__ Wlo,
    const float* __restrict__ bias,
    unsigned short* __restrict__ Ohi, unsigned short* __restrict__ Olo, int N) {
  __shared__ unsigned short sAhi[128 * 32], sAlo[128 * 32];
  __shared__ unsigned short sBhi[128 * 32], sBlo[128 * 32];
  int t = threadIdx.x;
  int lane = t & 63;
  int w = t >> 6;
  int wr = (w >> 1) * 64, wc = (w & 1) * 64;
  int block_row = blockIdx.x * 128;

  f32x4 acc[4][4];
#pragma unroll
  for (int m = 0; m < 4; ++m)
#pragma unroll
    for (int n = 0; n < 4; ++n) acc[m][n] = f32x4{0.f, 0.f, 0.f, 0.f};

  int kg = lane & 3;        // 16B group within 64B row
  int rr = lane >> 2;       // 0..15 row-within-chunk
  int fr = lane & 15;       // fragment row/col
  int fkb = (lane >> 4) * 16;  // fragment k byte offset

  for (int kt = 0; kt < 8; ++kt) {
    // ---- stage 32KB: wave w fills one buffer (8 x 1KB chunks) ----
    {
      const unsigned short* gsrc;
      unsigned short* lbase;
      int isA = (w < 2);
      if (w == 0) { gsrc = (kt < 4) ? A1hi : A2hi; lbase = sAhi; }
      else if (w == 1) { gsrc = (kt < 4) ? A1lo : A2lo; lbase = sAlo; }
      else if (w == 2) { gsrc = Whi; lbase = sBhi; }
      else { gsrc = Wlo; lbase = sBlo; }
#pragma unroll
      for (int c = 0; c < 8; ++c) {
        int idx = c * 16 + rr;  // A: row; B: col
        const char* src;
        if (isA) {
          int rg = block_row + idx;
          if (rg > N - 1) rg = N - 1;
          src = (const char*)gsrc + (size_t)rg * 256 + (kt & 3) * 64 + kg * 16;
        } else {
          src = (const char*)gsrc + (size_t)idx * 512 + kt * 64 + kg * 16;
        }
        gload_lds16((void*)src, (char*)lbase + c * 1024);
      }
    }
    __syncthreads();
    // ---- fragments + 48 MFMA ----
    bf16x8 a_hi[4], a_lo[4], b_hi[4], b_lo[4];
#pragma unroll
    for (int m = 0; m < 4; ++m) {
      int row = wr + m * 16 + fr;
      a_hi[m] = *reinterpret_cast<const bf16x8*>((const char*)sAhi + row * 64 + fkb);
      a_lo[m] = *reinterpret_cast<const bf16x8*>((const char*)sAlo + row * 64 + fkb);
    }
#pragma unroll
    for (int n = 0; n < 4; ++n) {
      int col = wc + n * 16 + fr;
      b_hi[n] = *reinterpret_cast<const bf16x8*>((const char*)sBhi + col * 64 + fkb);
      b_lo[n] = *reinterpret_cast<const bf16x8*>((const char*)sBlo + col * 64 + fkb);
    }
#pragma unroll
    for (int m = 0; m < 4; ++m)
#pragma unroll
      for (int n = 0; n < 4; ++n) {
        acc[m][n] = __builtin_amdgcn_mfma_f32_16x16x32_bf16(a_hi[m], b_hi[n], acc[m][n], 0, 0, 0);
        acc[m][n] = __builtin_amdgcn_mfma_f32_16x16x32_bf16(a_hi[m], b_lo[n], acc[m][n], 0, 0, 0);
        acc[m][n] = __builtin_amdgcn_mfma_f32_16x16x32_bf16(a_lo[m], b_hi[n], acc[m][n], 0, 0, 0);
      }
    __syncthreads();
  }

  // ---- epilogue: bias + relu -> bf16 hi/lo ----
  float bv[4];
#pragma unroll
  for (int n = 0; n < 4; ++n) bv[n] = bias[wc + n * 16 + (lane & 15)];
#pragma unroll
  for (int m = 0; m < 4; ++m) {
#pragma unroll
    for (int n = 0; n < 4; ++n) {
#pragma unroll
      for (int j = 0; j < 4; ++j) {
        int row_l = wr + m * 16 + (lane >> 4) * 4 + j;
        int g = block_row + row_l;
        if (g < N) {
          int col = wc + n * 16 + (lane & 15);
          float v = fmaxf(acc[m][n][j] + bv[n], 0.f);
          unsigned short h = f32_to_bf16(v);
          Ohi[(size_t)g * 128 + col] = h;
          Olo[(size_t)g * 128 + col] = f32_to_bf16(v - bf16_to_f32(h));
        }
      }
    }
  }
}

// Final: Out[N][16] = H[N][128] @ W[128][16] + b; H reconstructed from hi+lo.
__global__ __launch_bounds__(256) void k_final(const unsigned short* __restrict__ Hhi,
                                               const unsigned short* __restrict__ Hlo,
                                               const float* __restrict__ W,
                                               const float* __restrict__ b,
                                               float* __restrict__ Out, int N) {
  __shared__ float sH[16][128];
  __shared__ float sW[128][16];
  __shared__ float sb[16];
  int t = threadIdx.x;
  int node0 = blockIdx.x * 16;
  {
    int row = t >> 4, q = t & 15;  // 8 elems each
    int g = node0 + row;
    if (g < N) {
      uint4 hv = *reinterpret_cast<const uint4*>(&Hhi[(size_t)g * 128 + q * 8]);
      uint4 lv = *reinterpret_cast<const uint4*>(&Hlo[(size_t)g * 128 + q * 8]);
      const unsigned short* hp = (const unsigned short*)&hv;
      const unsigned short* lp = (const unsigned short*)&lv;
#pragma unroll
      for (int e = 0; e < 8; ++e)
        sH[row][q * 8 + e] = bf16_to_f32(hp[e]) + bf16_to_f32(lp[e]);
    } else {
#pragma unroll
      for (int e = 0; e < 8; ++e) sH[row][q * 8 + e] = 0.f;
    }
  }
  for (int j = t; j < 512; j += 256) {
    int row = j >> 2, q = j & 3;
    *reinterpret_cast<float4*>(&sW[row][q * 4]) =
        *reinterpret_cast<const float4*>(&W[(size_t)row * 16 + q * 4]);
  }
  if (t < 16) sb[t] = b[t];
  __syncthreads();
  int node = t >> 4, col = t & 15;
  float acc = sb[col];
#pragma unroll 8
  for (int k = 0; k < 128; ++k) acc = fmaf(sH[node][k], sW[k][col], acc);
  int g = node0 + node;
  if (g < N) Out[(size_t)g * 16 + col] = acc;
}

extern "C" void kernel_launch(void* const* d_in, const int* in_sizes, int n_in,
                              void* d_out, int out_size, void* d_ws, size_t ws_size,
                              hipStream_t stream) {
  if (n_in < 13) return;
  const float* x = (const float*)d_in[0];
  const int* ei = (const int*)d_in[1];
  const float* W1l = (const float*)d_in[2];
  const float* b1 = (const float*)d_in[3];
  const float* W1r = (const float*)d_in[4];
  const float* W2l = (const float*)d_in[5];
  const float* b2 = (const float*)d_in[6];
  const float* W2r = (const float*)d_in[7];
  const float* W3l = (const float*)d_in[8];
  const float* b3 = (const float*)d_in[9];
  const float* W3r = (const float*)d_in[10];
  const float* Wlin = (const float*)d_in[11];
  const float* blin = (const float*)d_in[12];
  float* out = (float*)d_out;

  const int N = in_sizes[0] / 128;
  const int E = in_sizes[1] / 2;

  char* w = (char*)d_ws;
  size_t off = 0;
  auto alloc = [&](size_t bytes) -> void* {
    off = (off + 255) & ~(size_t)255;
    void* p = (void*)(w + off);
    off += bytes;
    return p;
  };
  size_t actB = (size_t)N * 128 * 2;
  unsigned short* Xhi = (unsigned short*)alloc(actB);
  unsigned short* Xlo = (unsigned short*)alloc(actB);
  unsigned short* Ahi = (unsigned short*)alloc(actB);
  unsigned short* Alo = (unsigned short*)alloc(actB);
  unsigned short* Mhi = (unsigned short*)alloc(actB);
  unsigned short* Mlo = (unsigned short*)alloc(actB);
  unsigned short* Wt[6];
  for (int i = 0; i < 6; ++i) Wt[i] = (unsigned short*)alloc(128 * 256 * 2);
  int* deg = (int*)alloc((size_t)N * 4);
  int* row_ptr = (int*)alloc((size_t)(N + 1) * 4);
  int* col_idx = (int*)alloc((size_t)E * 4);
  int* erank = (int*)alloc((size_t)E * 4);
  float* invdeg = (float*)alloc((size_t)N * 4);
  int* flag = (int*)alloc(4);
  int* bsum = (int*)alloc((size_t)1024 * 4);
  (void)ws_size;

  const int nbScan = (N + 1023) / 1024;

  // CSR build + operand prep
  k_zero_i32<<<(N + 255) / 256, 256, 0, stream>>>(deg, N);
  k_zero_i32<<<1, 256, 0, stream>>>(flag, 1);
  k_detect<<<1, 256, 0, stream>>>(ei, flag);
  k_count<<<(E + 255) / 256, 256, 0, stream>>>(ei, flag, deg, erank, E);
  k_split<<<(N * 32 + 255) / 256, 256, 0, stream>>>(x, Xhi, Xlo, N * 32);
  k_prep_w<<<128, 256, 0, stream>>>(W1l, W1r, Wt[0], Wt[1]);
  k_prep_w<<<128, 256, 0, stream>>>(W2l, W2r, Wt[2], Wt[3]);
  k_prep_w<<<128, 256, 0, stream>>>(W3l, W3r, Wt[4], Wt[5]);
  k_scan1<<<nbScan, 256, 0, stream>>>(deg, bsum, N);
  k_scan2<<<1, 1024, 0, stream>>>(bsum, row_ptr, nbScan, N);
  k_scan3<<<nbScan, 256, 0, stream>>>(deg, bsum, row_ptr, invdeg, N);
  k_fill<<<(E + 255) / 256, 256, 0, stream>>>(ei, flag, row_ptr, erank, col_idx, E);

  int aggBlocks = (N * 64 + 255) / 256;
  int gemmBlocks = (N + 127) / 128;

  // layer 1: X -> A (h1)
  k_aggregate<<<aggBlocks, 256, 0, stream>>>(Xhi, row_ptr, col_idx, invdeg,
                                             (unsigned int*)Mhi, (unsigned int*)Mlo, N);
  k_mfma_gemm<<<gemmBlocks, 256, 0, stream>>>(Mhi, Mlo, Xhi, Xlo, Wt[0], Wt[1], b1,
                                              Ahi, Alo, N);
  // layer 2: A -> X (h2)
  k_aggregate<<<aggBlocks, 256, 0, stream>>>(Ahi, row_ptr, col_idx, invdeg,
                                             (unsigned int*)Mhi, (unsigned int*)Mlo, N);
  k_mfma_gemm<<<gemmBlocks, 256, 0, stream>>>(Mhi, Mlo, Ahi, Alo, Wt[2], Wt[3], b2,
                                              Xhi, Xlo, N);
  // layer 3: X -> A (h3)
  k_aggregate<<<aggBlocks, 256, 0, stream>>>(Xhi, row_ptr, col_idx, invdeg,
                                             (unsigned int*)Mhi, (unsigned int*)Mlo, N);
  k_mfma_gemm<<<gemmBlocks, 256, 0, stream>>>(Mhi, Mlo, Xhi, Xlo, Wt[4], Wt[5], b3,
                                              Ahi, Alo, N);
  // final linear
  k_final<<<(N + 15) / 16, 256, 0, stream>>>(Ahi, Alo, Wlin, blin, out, N);
}